// Round 14
// baseline (1112.439 us; speedup 1.0000x reference)
//
#include <hip/hip_runtime.h>
#include <hip/hip_bf16.h>

typedef __attribute__((ext_vector_type(8))) short short8;
typedef __attribute__((ext_vector_type(8))) unsigned short ushort8;
typedef __attribute__((ext_vector_type(4))) float floatx4;
typedef __attribute__((ext_vector_type(16))) float floatx16;
typedef __attribute__((ext_vector_type(4))) unsigned int uint4v;
typedef __attribute__((ext_vector_type(2))) unsigned int uint2v;

#define DEVINL static __device__ __forceinline__

DEVINL float b2f(unsigned short s){ union{unsigned u; float f;} v; v.u=((unsigned)s)<<16; return v.f; }
DEVINL unsigned fbits(float f){ union{float f; unsigned u;} v; v.f=f; return v.u; }
DEVINL unsigned pack2(float f0, float f1){
  return __builtin_amdgcn_perm(fbits(f1)+0x8000u, fbits(f0)+0x8000u, 0x07060302u);
}
// single-instruction packed cvt (RNE), gfx950
DEVINL unsigned cvt_pk(float lo, float hi){
  unsigned r;
  asm("v_cvt_pk_bf16_f32 %0, %1, %2" : "=v"(r) : "v"(lo), "v"(hi));
  return r;
}
// tanh(x) = 1 - 2/(1+e^{2x}); exact limits at +-inf
DEVINL float tanh_fast(float v){
  float ex = __builtin_amdgcn_exp2f(v * 2.885390081777927f);   // e^{2v}
  return 1.f - 2.f*__builtin_amdgcn_rcpf(1.f + ex);
}

constexpr int Sc=256, Hc=768, Nc=128, HIDc=1024, Lc=16;

// ================= merged prep kernel =================
__global__ __launch_bounds__(256) void k_prep(const float* __restrict__ AH,
                                              const int* __restrict__ ST,
                                              const float* __restrict__ W1,
                                              const float* __restrict__ W2,
                                              unsigned short* __restrict__ con,
                                              unsigned short* __restrict__ w1mF,
                                              unsigned short* __restrict__ w2F2,
                                              unsigned short* __restrict__ wPQF){
  int bid = blockIdx.x, t = threadIdx.x;
  if (bid < 512) {
    int row = bid;                      // b*128 + n
    int b = row >> 7;
    int st = ST[row];
    const float* src = AH + ((size_t)(b*Sc + st))*Hc;
    unsigned short* dst = con + (size_t)row*Hc;
    if (t < 192) {
      float4 v = reinterpret_cast<const float4*>(src)[t];
      uint2v o = { pack2(v.x, v.y), pack2(v.z, v.w) };
      *reinterpret_cast<uint2v*>(dst + 4*t) = o;
    }
  } else if (bid < 896) {
    int sid = (bid - 512)*256 + t;      // 0..98303
    int l = sid & 63, kc = (sid >> 6) % 48, ht = sid / (48*64);
    int k = kc*16 + (l >> 5)*8;
    int h = ht*32 + (l & 31);
    const float* wp = W1 + (size_t)(2304 + k)*1024 + h;
    uint4v d;
    d[0] = pack2(wp[0],      wp[1024]);
    d[1] = pack2(wp[2*1024], wp[3*1024]);
    d[2] = pack2(wp[4*1024], wp[5*1024]);
    d[3] = pack2(wp[6*1024], wp[7*1024]);
    *reinterpret_cast<uint4v*>(w1mF + (size_t)sid*8) = d;
  } else if (bid < 912) {
    int gid = (bid - 896)*256 + t;      // 0..4095
    int l = gid & 63, chunk = gid >> 6;
    int row = l & 31, s = l >> 5;
    unsigned u[4];
    #pragma unroll
    for (int p = 0; p < 4; ++p) {
      int e0 = 2*p, e1 = 2*p + 1;
      int h0 = chunk*16 + 4*s + (e0 & 3) + 8*(e0 >> 2);
      int h1 = chunk*16 + 4*s + (e1 & 3) + 8*(e1 >> 2);
      float v0 = (row < 16) ? W2[(size_t)h0*Lc + row] : 0.f;
      float v1 = (row < 16) ? W2[(size_t)h1*Lc + row] : 0.f;
      u[p] = pack2(v0, v1);
    }
    uint4v d = { u[0], u[1], u[2], u[3] };
    *reinterpret_cast<uint4v*>(w2F2 + (size_t)gid*8) = d;
  } else {
    int sid = (bid - 912)*256 + t;      // 0..196607
    int lane = sid & 63, kcq = (sid >> 6) % 24, ht = sid / (24*64);
    int col = lane & 15, seg = lane >> 4;
    int hp = ht*16 + col;
    int kb = kcq*32 + seg*8;
    uint4v d;
    if (hp < 1024) {
      const float* w0 = W1 + (size_t)kb*1024 + hp;
      const float* wd = W1 + (size_t)(1536+kb)*1024 + hp;
      d[0] = pack2(w0[0]+wd[0],           w0[1024]+wd[1024]);
      d[1] = pack2(w0[2*1024]+wd[2*1024], w0[3*1024]+wd[3*1024]);
      d[2] = pack2(w0[4*1024]+wd[4*1024], w0[5*1024]+wd[5*1024]);
      d[3] = pack2(w0[6*1024]+wd[6*1024], w0[7*1024]+wd[7*1024]);
    } else {
      int hq = hp - 1024;
      const float* wc = W1 + (size_t)(768+kb)*1024 + hq;
      const float* wd = W1 + (size_t)(1536+kb)*1024 + hq;
      d[0] = pack2(wc[0]-wd[0],           wc[1024]-wd[1024]);
      d[1] = pack2(wc[2*1024]-wd[2*1024], wc[3*1024]-wd[3*1024]);
      d[2] = pack2(wc[4*1024]-wd[4*1024], wc[5*1024]-wd[5*1024]);
      d[3] = pack2(wc[6*1024]-wd[6*1024], wc[7*1024]-wd[7*1024]);
    }
    *reinterpret_cast<uint4v*>(wPQF + (size_t)sid*8) = d;
  }
}

// ---------------- P/Q via MFMA: out[512 rows][2048 cols] ----------------
__global__ __launch_bounds__(256) void k_pq(const unsigned short* __restrict__ con,
                                            const unsigned short* __restrict__ wPQF,
                                            float* __restrict__ P, float* __restrict__ Q){
  int rg = blockIdx.x >> 4, hg = blockIdx.x & 15;     // 16 rowgroups x 16 colgroups
  int t = threadIdx.x, w = t >> 6, lane = t & 63;
  int colh = lane & 15, rseg = lane >> 4;
  floatx4 zero = {0.f,0.f,0.f,0.f};
  floatx4 acc[2][2] = {{zero,zero},{zero,zero}};
  const unsigned short* a0p = con + (size_t)(rg*32 + colh)*Hc + rseg*8;
  const unsigned short* a1p = a0p + 16*Hc;
  const unsigned short* b0p = wPQF + (((size_t)((hg*8 + w*2)*24)) << 9) + (lane << 3);
  const unsigned short* b1p = b0p + (24 << 9);
  #pragma unroll
  for (int kc = 0; kc < 24; ++kc) {
    short8 af0 = *reinterpret_cast<const short8*>(a0p + kc*32);
    short8 af1 = *reinterpret_cast<const short8*>(a1p + kc*32);
    short8 bf0 = *reinterpret_cast<const short8*>(b0p + ((size_t)kc << 9));
    short8 bf1 = *reinterpret_cast<const short8*>(b1p + ((size_t)kc << 9));
    acc[0][0] = __builtin_amdgcn_mfma_f32_16x16x32_bf16(af0, bf0, acc[0][0], 0,0,0);
    acc[0][1] = __builtin_amdgcn_mfma_f32_16x16x32_bf16(af0, bf1, acc[0][1], 0,0,0);
    acc[1][0] = __builtin_amdgcn_mfma_f32_16x16x32_bf16(af1, bf0, acc[1][0], 0,0,0);
    acc[1][1] = __builtin_amdgcn_mfma_f32_16x16x32_bf16(af1, bf1, acc[1][1], 0,0,0);
  }
  #pragma unroll
  for (int m = 0; m < 2; ++m)
    #pragma unroll
    for (int n = 0; n < 2; ++n)
      #pragma unroll
      for (int rr = 0; rr < 4; ++rr) {
        int row = rg*32 + m*16 + rseg*4 + rr;
        int hp = hg*128 + w*32 + n*16 + colh;
        float val = acc[m][n][rr];
        if (hg < 8) P[(size_t)row*HIDc + hp] = val;
        else        Q[(size_t)row*HIDc + (hp - 1024)] = val;
      }
}

// ---------------- fused main kernel: one block per (b,i,jhalf) ----------------
// OCCUPANCY build: 1024 blocks x 1024 threads (16 waves, 1 block/CU,
// 4 waves/SIMD = 2x r13). Wave tile HALVED to 2ht x 2jt (acc 64 AGPR) so a
// wave fits the 128-reg cap that 16 resident waves require. Same conF (96KB),
// same barrier-free K loop (depth-1 wx prefetch; TLP hides the rest), same
// epilogue re-indexed (htg = w*2+m), 64-row reduction buffer.
__global__ __launch_bounds__(1024, 1) void k_main(const unsigned short* __restrict__ con,
    const unsigned short* __restrict__ w1mF, const unsigned short* __restrict__ w2F2,
    const float* __restrict__ P, const float* __restrict__ Q, const float* __restrict__ b1,
    const float* __restrict__ b2v, float* __restrict__ out){
  __shared__ __align__(16) unsigned short conF[2*48*64*8];   // 96KB [jt][kc][lane][e]
  __shared__ float a_row[768];
  __shared__ float Pi_lds[1024];

  // XCD-bijective decode: 8 XCDs each own one (b,jh)
  int bid = blockIdx.x;
  int xcd = bid & 7, i = bid >> 3;
  int b = xcd >> 1, jh = xcd & 1;
  int bi = b*128 + i, bN = b*128;
  int t = threadIdx.x, w = t >> 6, lane = t & 63;
  int col32 = lane & 31, hi5 = lane >> 5;

  if (t < 96) {
    ushort8 c8 = *reinterpret_cast<const ushort8*>(con + (size_t)(bN + i)*Hc + t*8);
    #pragma unroll
    for (int e = 0; e < 8; ++e) a_row[t*8 + e] = b2f((unsigned short)c8[e]);
  }
  if (t >= 512 && t < 768) {
    int tt = t - 512;
    float4 p4 = reinterpret_cast<const float4*>(P + (size_t)(bN + i)*HIDc)[tt];
    float4 b4 = reinterpret_cast<const float4*>(b1)[tt];
    float4 s4 = { p4.x + b4.x, p4.y + b4.y, p4.z + b4.z, p4.w + b4.w };
    *reinterpret_cast<float4*>(&Pi_lds[4*tt]) = s4;
  }
  // ---- stage conF once: 6 slots of 16B per thread ----
  {
    const unsigned short* conI = con + (size_t)(bN + i)*Hc;
    #pragma unroll
    for (int r = 0; r < 6; ++r) {
      int s = r*1024 + t;                   // 0..6143
      int jt = (s >= 3072) ? 1 : 0;
      int rem = s - jt*3072;
      int kc = rem >> 6, ln = rem & 63;
      int j = jh*64 + jt*32 + (ln & 31);
      int kb = kc*16 + ((ln >> 5) << 3);
      ushort8 c8 = *reinterpret_cast<const ushort8*>(con + (size_t)(bN + j)*Hc + kb);
      ushort8 a8 = *reinterpret_cast<const ushort8*>(conI + kb);
      uint4v d;
      d[0] = cvt_pk(b2f(a8[0])*b2f(c8[0]), b2f(a8[1])*b2f(c8[1]));
      d[1] = cvt_pk(b2f(a8[2])*b2f(c8[2]), b2f(a8[3])*b2f(c8[3]));
      d[2] = cvt_pk(b2f(a8[4])*b2f(c8[4]), b2f(a8[5])*b2f(c8[5]));
      d[3] = cvt_pk(b2f(a8[6])*b2f(c8[6]), b2f(a8[7])*b2f(c8[7]));
      *reinterpret_cast<uint4v*>(conF + (size_t)s*8) = d;
    }
  }
  __syncthreads();

  // ---- barrier-free K loop: wave w owns ht tiles w*2, w*2+1 ----
  const unsigned short* wp = w1mF + (((size_t)(w*2)*48) << 9) + (lane << 3);
  const unsigned short* yb = conF + (lane << 3);
  constexpr size_t HTS = (size_t)48 << 9;   // ht stride (elems)
  constexpr size_t KCS = (size_t)1 << 9;    // kc stride (elems)
  constexpr size_t JTS = (size_t)48 << 9;   // conF jt stride

  floatx16 a00, a01, a10, a11;              // [ht][jt]
  #pragma unroll
  for (int r = 0; r < 16; ++r) { a00[r]=0.f; a01[r]=0.f; a10[r]=0.f; a11[r]=0.f; }

#define KCL(K) ((K) < 48 ? (K) : 47)
#define LOADW(P0,P1, KC) { \
  size_t o_ = (size_t)KCL(KC)*KCS; \
  P0 = *reinterpret_cast<const ushort8*>(wp + 0*HTS + o_); \
  P1 = *reinterpret_cast<const ushort8*>(wp + 1*HTS + o_); }
#define LOADY(Y0,Y1, KC) { \
  size_t o_ = (size_t)(KC)*KCS; \
  Y0 = *reinterpret_cast<const short8*>(yb + o_); \
  Y1 = *reinterpret_cast<const short8*>(yb + JTS + o_); }
#define MFMA4(U0,U1, Z0,Z1) { \
  __builtin_amdgcn_s_setprio(1); \
  a00 = __builtin_amdgcn_mfma_f32_32x32x16_bf16(U0, Z0, a00, 0,0,0); \
  a01 = __builtin_amdgcn_mfma_f32_32x32x16_bf16(U0, Z1, a01, 0,0,0); \
  a10 = __builtin_amdgcn_mfma_f32_32x32x16_bf16(U1, Z0, a10, 0,0,0); \
  a11 = __builtin_amdgcn_mfma_f32_32x32x16_bf16(U1, Z1, a11, 0,0,0); \
  __builtin_amdgcn_s_setprio(0); }

  {
    ushort8 wa0,wa1, wb0,wb1;
    short8 y0,y1, z0,z1;
    LOADW(wa0,wa1, 0);
    #pragma unroll
    for (int p = 0; p < 24; ++p) {
      LOADW(wb0,wb1, 2*p+1);
      LOADY(y0,y1, 2*p);
      MFMA4(wa0,wa1, y0,y1);
      LOADW(wa0,wa1, 2*p+2);
      LOADY(z0,z1, 2*p+1);
      MFMA4(wb0,wb1, z0,z1);
    }
  }
#undef KCL
#undef LOADW
#undef LOADY
#undef MFMA4

  // ---- epilogue: tanh in-register -> GEMM2 (zero shuffle) ----
  floatx16 acc2_0, acc2_1;
  #pragma unroll
  for (int r = 0; r < 16; ++r) { acc2_0[r] = 0.f; acc2_1[r] = 0.f; }

#define EPI(M, AJ0, AJ1) { \
  int htg = w*2 + (M); \
  const unsigned short* w2p = w2F2 + (((size_t)(htg*2)) << 9) + (lane << 3); \
  ushort8 wf0 = *reinterpret_cast<const ushort8*>(w2p); \
  ushort8 wf1 = *reinterpret_cast<const ushort8*>(w2p + 512); \
  int hbase = htg*32 + 4*hi5; \
  _Pragma("unroll") \
  for (int jt = 0; jt < 2; ++jt) { \
    const floatx16& a = (jt==0) ? AJ0 : AJ1; \
    floatx16& a2 = (jt==0) ? acc2_0 : acc2_1; \
    const float* qrow = Q + (size_t)(bN + jh*64 + jt*32 + col32)*HIDc + hbase; \
    unsigned hfu[2][4]; \
    _Pragma("unroll") \
    for (int q = 0; q < 4; ++q) { \
      floatx4 qv = *reinterpret_cast<const floatx4*>(qrow + 8*q); \
      floatx4 pf = *reinterpret_cast<const floatx4*>(&Pi_lds[hbase + 8*q]); \
      float t0 = tanh_fast(a[q*4+0] + pf[0] + qv[0]); \
      float t1 = tanh_fast(a[q*4+1] + pf[1] + qv[1]); \
      float t2 = tanh_fast(a[q*4+2] + pf[2] + qv[2]); \
      float t3 = tanh_fast(a[q*4+3] + pf[3] + qv[3]); \
      hfu[q >> 1][(q & 1)*2 + 0] = cvt_pk(t0, t1); \
      hfu[q >> 1][(q & 1)*2 + 1] = cvt_pk(t2, t3); \
    } \
    union { uint4v u; short8 s; } f0, f1; \
    f0.u[0]=hfu[0][0]; f0.u[1]=hfu[0][1]; f0.u[2]=hfu[0][2]; f0.u[3]=hfu[0][3]; \
    f1.u[0]=hfu[1][0]; f1.u[1]=hfu[1][1]; f1.u[2]=hfu[1][2]; f1.u[3]=hfu[1][3]; \
    a2 = __builtin_amdgcn_mfma_f32_32x32x16_bf16(wf0, f0.s, a2, 0,0,0); \
    a2 = __builtin_amdgcn_mfma_f32_32x32x16_bf16(wf1, f1.s, a2, 0,0,0); \
  } }

  EPI(0, a00, a01);
  EPI(1, a10, a11);
#undef EPI

  // ---- cross-wave reduction (reuse conF as 64KB red buffer) ----
  __syncthreads();                       // all conF reads done
  float* red = reinterpret_cast<float*>(conF);   // [64][64][4]: row = w*4 + jt*2 + q
  #pragma unroll
  for (int q = 0; q < 2; ++q) {
    floatx4 v0 = { acc2_0[q*4+0], acc2_0[q*4+1], acc2_0[q*4+2], acc2_0[q*4+3] };
    floatx4 v1 = { acc2_1[q*4+0], acc2_1[q*4+1], acc2_1[q*4+2], acc2_1[q*4+3] };
    *reinterpret_cast<floatx4*>(&red[((w*4 + 0*2 + q)*64 + lane)*4]) = v0;
    *reinterpret_cast<floatx4*>(&red[((w*4 + 1*2 + q)*64 + lane)*4]) = v1;
  }
  __syncthreads();
  if (w < 4) {
    int jtR = w & 1, qR = w >> 1;
    floatx4 s = {0.f,0.f,0.f,0.f};
    #pragma unroll
    for (int src = 0; src < 16; ++src) {
      floatx4 v = *reinterpret_cast<const floatx4*>(&red[((src*4 + jtR*2 + qR)*64 + lane)*4]);
      s[0]+=v[0]; s[1]+=v[1]; s[2]+=v[2]; s[3]+=v[3];
    }
    int jout = jh*64 + jtR*32 + col32;
    int Lb = 8*qR + 4*hi5;
    float* op = out + ((size_t)bi*Nc + jout)*Lc + Lb;
    #pragma unroll
    for (int c = 0; c < 4; ++c) op[c] = s[c] + b2v[Lb + c];
  }
}

extern "C" void kernel_launch(void* const* d_in, const int* in_sizes, int n_in,
                              void* d_out, int out_size, void* d_ws, size_t ws_size,
                              hipStream_t stream) {
  const float* AH = (const float*)d_in[0];
  const int*   ST = (const int*)d_in[1];
  const float* W1 = (const float*)d_in[2];
  const float* b1 = (const float*)d_in[3];
  const float* W2 = (const float*)d_in[4];
  const float* b2 = (const float*)d_in[5];
  float* out = (float*)d_out;

  char* ws = (char*)d_ws;
  unsigned short* con  = (unsigned short*)ws;                //   786,432 B
  unsigned short* w1mF = (unsigned short*)(ws +   786432);   // 1,572,864 B
  unsigned short* wPQF = (unsigned short*)(ws +  2359296);   // 3,145,728 B
  float* P = (float*)(ws + 5505024);                         // 2,097,152 B
  float* Q = (float*)(ws + 7602176);                         // 2,097,152 B
  unsigned short* w2F2 = (unsigned short*)(ws + 9699328);    //    65,536 B

  k_prep<<<1680, 256, 0, stream>>>(AH, ST, W1, W2, con, w1mF, w2F2, wPQF);
  k_pq<<<256, 256, 0, stream>>>(con, wPQF, P, Q);
  k_main<<<1024, 1024, 0, stream>>>(con, w1mF, w2F2, P, Q, b1, b2, out);
}

// Round 15
// 162.807 us; speedup vs baseline: 6.8329x; 6.8329x over previous
//
#include <hip/hip_runtime.h>
#include <hip/hip_bf16.h>

typedef __attribute__((ext_vector_type(8))) short short8;
typedef __attribute__((ext_vector_type(8))) unsigned short ushort8;
typedef __attribute__((ext_vector_type(4))) float floatx4;
typedef __attribute__((ext_vector_type(16))) float floatx16;
typedef __attribute__((ext_vector_type(4))) unsigned int uint4v;
typedef __attribute__((ext_vector_type(2))) unsigned int uint2v;

#define DEVINL static __device__ __forceinline__

DEVINL float b2f(unsigned short s){ union{unsigned u; float f;} v; v.u=((unsigned)s)<<16; return v.f; }
DEVINL unsigned fbits(float f){ union{float f; unsigned u;} v; v.f=f; return v.u; }
DEVINL unsigned pack2(float f0, float f1){
  return __builtin_amdgcn_perm(fbits(f1)+0x8000u, fbits(f0)+0x8000u, 0x07060302u);
}
// single-instruction packed cvt (RNE), gfx950
DEVINL unsigned cvt_pk(float lo, float hi){
  unsigned r;
  asm("v_cvt_pk_bf16_f32 %0, %1, %2" : "=v"(r) : "v"(lo), "v"(hi));
  return r;
}
// tanh(x) = 1 - 2/(1+e^{2x}); exact limits at +-inf
DEVINL float tanh_fast(float v){
  float ex = __builtin_amdgcn_exp2f(v * 2.885390081777927f);   // e^{2v}
  return 1.f - 2.f*__builtin_amdgcn_rcpf(1.f + ex);
}
DEVINL void gload_lds16(const void* g, void* l){
  __builtin_amdgcn_global_load_lds(
    (const __attribute__((address_space(1))) unsigned int*)g,
    (__attribute__((address_space(3))) unsigned int*)l, 16, 0, 0);
}

constexpr int Sc=256, Hc=768, Nc=128, HIDc=1024, Lc=16;

// ================= merged prep kernel =================
__global__ __launch_bounds__(256) void k_prep(const float* __restrict__ AH,
                                              const int* __restrict__ ST,
                                              const float* __restrict__ W1,
                                              const float* __restrict__ W2,
                                              unsigned short* __restrict__ con,
                                              unsigned short* __restrict__ w1mF,
                                              unsigned short* __restrict__ w2F2,
                                              unsigned short* __restrict__ wPQF){
  int bid = blockIdx.x, t = threadIdx.x;
  if (bid < 512) {
    int row = bid;                      // b*128 + n
    int b = row >> 7;
    int st = ST[row];
    const float* src = AH + ((size_t)(b*Sc + st))*Hc;
    unsigned short* dst = con + (size_t)row*Hc;
    if (t < 192) {
      float4 v = reinterpret_cast<const float4*>(src)[t];
      uint2v o = { pack2(v.x, v.y), pack2(v.z, v.w) };
      *reinterpret_cast<uint2v*>(dst + 4*t) = o;
    }
  } else if (bid < 896) {
    int sid = (bid - 512)*256 + t;      // 0..98303
    int l = sid & 63, kc = (sid >> 6) % 48, ht = sid / (48*64);
    int k = kc*16 + (l >> 5)*8;
    int h = ht*32 + (l & 31);
    const float* wp = W1 + (size_t)(2304 + k)*1024 + h;
    uint4v d;
    d[0] = pack2(wp[0],      wp[1024]);
    d[1] = pack2(wp[2*1024], wp[3*1024]);
    d[2] = pack2(wp[4*1024], wp[5*1024]);
    d[3] = pack2(wp[6*1024], wp[7*1024]);
    *reinterpret_cast<uint4v*>(w1mF + (size_t)sid*8) = d;
  } else if (bid < 912) {
    int gid = (bid - 896)*256 + t;      // 0..4095
    int l = gid & 63, chunk = gid >> 6;
    int row = l & 31, s = l >> 5;
    unsigned u[4];
    #pragma unroll
    for (int p = 0; p < 4; ++p) {
      int e0 = 2*p, e1 = 2*p + 1;
      int h0 = chunk*16 + 4*s + (e0 & 3) + 8*(e0 >> 2);
      int h1 = chunk*16 + 4*s + (e1 & 3) + 8*(e1 >> 2);
      float v0 = (row < 16) ? W2[(size_t)h0*Lc + row] : 0.f;
      float v1 = (row < 16) ? W2[(size_t)h1*Lc + row] : 0.f;
      u[p] = pack2(v0, v1);
    }
    uint4v d = { u[0], u[1], u[2], u[3] };
    *reinterpret_cast<uint4v*>(w2F2 + (size_t)gid*8) = d;
  } else {
    int sid = (bid - 912)*256 + t;      // 0..196607
    int lane = sid & 63, kcq = (sid >> 6) % 24, ht = sid / (24*64);
    int col = lane & 15, seg = lane >> 4;
    int hp = ht*16 + col;
    int kb = kcq*32 + seg*8;
    uint4v d;
    if (hp < 1024) {
      const float* w0 = W1 + (size_t)kb*1024 + hp;
      const float* wd = W1 + (size_t)(1536+kb)*1024 + hp;
      d[0] = pack2(w0[0]+wd[0],           w0[1024]+wd[1024]);
      d[1] = pack2(w0[2*1024]+wd[2*1024], w0[3*1024]+wd[3*1024]);
      d[2] = pack2(w0[4*1024]+wd[4*1024], w0[5*1024]+wd[5*1024]);
      d[3] = pack2(w0[6*1024]+wd[6*1024], w0[7*1024]+wd[7*1024]);
    } else {
      int hq = hp - 1024;
      const float* wc = W1 + (size_t)(768+kb)*1024 + hq;
      const float* wd = W1 + (size_t)(1536+kb)*1024 + hq;
      d[0] = pack2(wc[0]-wd[0],           wc[1024]-wd[1024]);
      d[1] = pack2(wc[2*1024]-wd[2*1024], wc[3*1024]-wd[3*1024]);
      d[2] = pack2(wc[4*1024]-wd[4*1024], wc[5*1024]-wd[5*1024]);
      d[3] = pack2(wc[6*1024]-wd[6*1024], wc[7*1024]-wd[7*1024]);
    }
    *reinterpret_cast<uint4v*>(wPQF + (size_t)sid*8) = d;
  }
}

// ------- P/Q via MFMA; P side fused with +b1 (epilogue reads it raw) -------
__global__ __launch_bounds__(256) void k_pq(const unsigned short* __restrict__ con,
                                            const unsigned short* __restrict__ wPQF,
                                            const float* __restrict__ b1,
                                            float* __restrict__ Pb, float* __restrict__ Q){
  int rg = blockIdx.x >> 4, hg = blockIdx.x & 15;     // 16 rowgroups x 16 colgroups
  int t = threadIdx.x, w = t >> 6, lane = t & 63;
  int colh = lane & 15, rseg = lane >> 4;
  floatx4 zero = {0.f,0.f,0.f,0.f};
  floatx4 acc[2][2] = {{zero,zero},{zero,zero}};
  const unsigned short* a0p = con + (size_t)(rg*32 + colh)*Hc + rseg*8;
  const unsigned short* a1p = a0p + 16*Hc;
  const unsigned short* b0p = wPQF + (((size_t)((hg*8 + w*2)*24)) << 9) + (lane << 3);
  const unsigned short* b1p = b0p + (24 << 9);
  #pragma unroll
  for (int kc = 0; kc < 24; ++kc) {
    short8 af0 = *reinterpret_cast<const short8*>(a0p + kc*32);
    short8 af1 = *reinterpret_cast<const short8*>(a1p + kc*32);
    short8 bf0 = *reinterpret_cast<const short8*>(b0p + ((size_t)kc << 9));
    short8 bf1 = *reinterpret_cast<const short8*>(b1p + ((size_t)kc << 9));
    acc[0][0] = __builtin_amdgcn_mfma_f32_16x16x32_bf16(af0, bf0, acc[0][0], 0,0,0);
    acc[0][1] = __builtin_amdgcn_mfma_f32_16x16x32_bf16(af0, bf1, acc[0][1], 0,0,0);
    acc[1][0] = __builtin_amdgcn_mfma_f32_16x16x32_bf16(af1, bf0, acc[1][0], 0,0,0);
    acc[1][1] = __builtin_amdgcn_mfma_f32_16x16x32_bf16(af1, bf1, acc[1][1], 0,0,0);
  }
  #pragma unroll
  for (int m = 0; m < 2; ++m)
    #pragma unroll
    for (int n = 0; n < 2; ++n)
      #pragma unroll
      for (int rr = 0; rr < 4; ++rr) {
        int row = rg*32 + m*16 + rseg*4 + rr;
        int hp = hg*128 + w*32 + n*16 + colh;
        float val = acc[m][n][rr];
        if (hg < 8) Pb[(size_t)row*HIDc + hp] = val + b1[hp];
        else        Q[(size_t)row*HIDc + (hp - 1024)] = val;
      }
}

// ---------------- fused main kernel: one block per (b,i,jhalf) ----------------
// r13 shell + wx via global_load_lds into a per-wave private 2-slot LDS ring
// (counted vmcnt(4), never 0 mid-loop). No VGPR round-trip for the wx stream.
// LDS: conF 96KB + wxR 64KB = 160KB (1 block/CU). Pi/a_row removed (Pb global).
__global__ __launch_bounds__(512, 2) void k_main(const unsigned short* __restrict__ con,
    const unsigned short* __restrict__ w1mF, const unsigned short* __restrict__ w2F2,
    const float* __restrict__ Pb, const float* __restrict__ Q,
    const float* __restrict__ b2v, float* __restrict__ out){
  __shared__ __align__(16) unsigned short conF[2*48*64*8];      // 96KB [jt][kc][lane][e]
  __shared__ __align__(16) unsigned short wxR[8][2][4][64][8];  // 64KB ring

  // XCD-bijective decode: 8 XCDs each own one (b,jh)
  int bid = blockIdx.x;
  int xcd = bid & 7, i = bid >> 3;
  int b = xcd >> 1, jh = xcd & 1;
  int bi = b*128 + i, bN = b*128;
  int t = threadIdx.x, w = t >> 6, lane = t & 63;
  int col32 = lane & 31, hi5 = lane >> 5;

  // ---- stage conF once: 12 slots of 16B per thread ----
  {
    const unsigned short* conI = con + (size_t)(bN + i)*Hc;
    #pragma unroll
    for (int r = 0; r < 12; ++r) {
      int s = r*512 + t;                    // 0..6143
      int jt = (s >= 3072) ? 1 : 0;
      int rem = s - jt*3072;
      int kc = rem >> 6, ln = rem & 63;
      int j = jh*64 + jt*32 + (ln & 31);
      int kb = kc*16 + ((ln >> 5) << 3);
      ushort8 c8 = *reinterpret_cast<const ushort8*>(con + (size_t)(bN + j)*Hc + kb);
      ushort8 a8 = *reinterpret_cast<const ushort8*>(conI + kb);
      uint4v d;
      d[0] = cvt_pk(b2f(a8[0])*b2f(c8[0]), b2f(a8[1])*b2f(c8[1]));
      d[1] = cvt_pk(b2f(a8[2])*b2f(c8[2]), b2f(a8[3])*b2f(c8[3]));
      d[2] = cvt_pk(b2f(a8[4])*b2f(c8[4]), b2f(a8[5])*b2f(c8[5]));
      d[3] = cvt_pk(b2f(a8[6])*b2f(c8[6]), b2f(a8[7])*b2f(c8[7]));
      *reinterpret_cast<uint4v*>(conF + (size_t)s*8) = d;
    }
  }
  __syncthreads();

  // ---- barrier-free K loop; wave w owns ht tiles w*4 .. w*4+3 ----
  const unsigned short* yb = conF + (lane << 3);
  constexpr size_t KCS = (size_t)1 << 9;    // kc stride (elems)
  constexpr size_t JTS = (size_t)48 << 9;   // conF jt stride

  floatx16 a0j0, a0j1, a1j0, a1j1, a2j0, a2j1, a3j0, a3j1;
  #pragma unroll
  for (int r = 0; r < 16; ++r) {
    a0j0[r]=0.f; a0j1[r]=0.f; a1j0[r]=0.f; a1j1[r]=0.f;
    a2j0[r]=0.f; a2j1[r]=0.f; a3j0[r]=0.f; a3j1[r]=0.f;
  }

#define STAGE(S, SLOT) { \
  _Pragma("unroll") \
  for (int ht_ = 0; ht_ < 4; ++ht_) { \
    const unsigned short* g_ = w1mF + (((size_t)((w*4 + ht_)*48 + (S))) << 9) + (lane << 3); \
    gload_lds16(g_, &wxR[w][SLOT][ht_][0][0]); \
  } }

  STAGE(0, 0);
  STAGE(1, 1);

  #pragma unroll
  for (int s = 0; s < 48; ++s) {
    if (s < 47) { asm volatile("s_waitcnt vmcnt(4)" ::: "memory"); }
    else        { asm volatile("s_waitcnt vmcnt(0)" ::: "memory"); }
    __builtin_amdgcn_sched_barrier(0);
    const int slot = s & 1;
    short8 x0 = *reinterpret_cast<const short8*>(&wxR[w][slot][0][lane][0]);
    short8 x1 = *reinterpret_cast<const short8*>(&wxR[w][slot][1][lane][0]);
    short8 x2 = *reinterpret_cast<const short8*>(&wxR[w][slot][2][lane][0]);
    short8 x3 = *reinterpret_cast<const short8*>(&wxR[w][slot][3][lane][0]);
    short8 y0 = *reinterpret_cast<const short8*>(yb + (size_t)s*KCS);
    short8 y1 = *reinterpret_cast<const short8*>(yb + JTS + (size_t)s*KCS);
    __builtin_amdgcn_s_setprio(1);
    a0j0 = __builtin_amdgcn_mfma_f32_32x32x16_bf16(x0, y0, a0j0, 0,0,0);
    a0j1 = __builtin_amdgcn_mfma_f32_32x32x16_bf16(x0, y1, a0j1, 0,0,0);
    a1j0 = __builtin_amdgcn_mfma_f32_32x32x16_bf16(x1, y0, a1j0, 0,0,0);
    a1j1 = __builtin_amdgcn_mfma_f32_32x32x16_bf16(x1, y1, a1j1, 0,0,0);
    a2j0 = __builtin_amdgcn_mfma_f32_32x32x16_bf16(x2, y0, a2j0, 0,0,0);
    a2j1 = __builtin_amdgcn_mfma_f32_32x32x16_bf16(x2, y1, a2j1, 0,0,0);
    a3j0 = __builtin_amdgcn_mfma_f32_32x32x16_bf16(x3, y0, a3j0, 0,0,0);
    a3j1 = __builtin_amdgcn_mfma_f32_32x32x16_bf16(x3, y1, a3j1, 0,0,0);
    __builtin_amdgcn_s_setprio(0);
    __builtin_amdgcn_sched_barrier(0);
    if (s < 46) STAGE(s + 2, slot);
  }
#undef STAGE

  // ---- epilogue: tanh in-register -> GEMM2 (zero shuffle), once ----
  floatx16 acc2_0, acc2_1;
  #pragma unroll
  for (int r = 0; r < 16; ++r) { acc2_0[r] = 0.f; acc2_1[r] = 0.f; }
  const float* PbI = Pb + (size_t)(bN + i)*HIDc;

#define EPI(M, AJ0, AJ1) { \
  int htg = w*4 + (M); \
  const unsigned short* w2p = w2F2 + (((size_t)(htg*2)) << 9) + (lane << 3); \
  ushort8 wf0 = *reinterpret_cast<const ushort8*>(w2p); \
  ushort8 wf1 = *reinterpret_cast<const ushort8*>(w2p + 512); \
  int hbase = htg*32 + 4*hi5; \
  _Pragma("unroll") \
  for (int jt = 0; jt < 2; ++jt) { \
    const floatx16& a = (jt==0) ? AJ0 : AJ1; \
    floatx16& a2 = (jt==0) ? acc2_0 : acc2_1; \
    const float* qrow = Q + (size_t)(bN + jh*64 + jt*32 + col32)*HIDc + hbase; \
    unsigned hfu[2][4]; \
    _Pragma("unroll") \
    for (int q = 0; q < 4; ++q) { \
      floatx4 qv = *reinterpret_cast<const floatx4*>(qrow + 8*q); \
      floatx4 pf = *reinterpret_cast<const floatx4*>(PbI + hbase + 8*q); \
      float t0 = tanh_fast(a[q*4+0] + pf[0] + qv[0]); \
      float t1 = tanh_fast(a[q*4+1] + pf[1] + qv[1]); \
      float t2 = tanh_fast(a[q*4+2] + pf[2] + qv[2]); \
      float t3 = tanh_fast(a[q*4+3] + pf[3] + qv[3]); \
      hfu[q >> 1][(q & 1)*2 + 0] = cvt_pk(t0, t1); \
      hfu[q >> 1][(q & 1)*2 + 1] = cvt_pk(t2, t3); \
    } \
    union { uint4v u; short8 s; } f0, f1; \
    f0.u[0]=hfu[0][0]; f0.u[1]=hfu[0][1]; f0.u[2]=hfu[0][2]; f0.u[3]=hfu[0][3]; \
    f1.u[0]=hfu[1][0]; f1.u[1]=hfu[1][1]; f1.u[2]=hfu[1][2]; f1.u[3]=hfu[1][3]; \
    a2 = __builtin_amdgcn_mfma_f32_32x32x16_bf16(wf0, f0.s, a2, 0,0,0); \
    a2 = __builtin_amdgcn_mfma_f32_32x32x16_bf16(wf1, f1.s, a2, 0,0,0); \
  } }

  EPI(0, a0j0, a0j1);
  EPI(1, a1j0, a1j1);
  EPI(2, a2j0, a2j1);
  EPI(3, a3j0, a3j1);
#undef EPI

  // ---- cross-wave reduction (reuse conF as 32KB red buffer) ----
  __syncthreads();                       // all conF/wxR reads done
  float* red = reinterpret_cast<float*>(conF);   // [32][64][4]: row = w*4 + jt*2 + q
  #pragma unroll
  for (int q = 0; q < 2; ++q) {
    floatx4 v0 = { acc2_0[q*4+0], acc2_0[q*4+1], acc2_0[q*4+2], acc2_0[q*4+3] };
    floatx4 v1 = { acc2_1[q*4+0], acc2_1[q*4+1], acc2_1[q*4+2], acc2_1[q*4+3] };
    *reinterpret_cast<floatx4*>(&red[((w*4 + 0*2 + q)*64 + lane)*4]) = v0;
    *reinterpret_cast<floatx4*>(&red[((w*4 + 1*2 + q)*64 + lane)*4]) = v1;
  }
  __syncthreads();
  if (w < 4) {
    int jtR = w & 1, qR = w >> 1;
    floatx4 s = {0.f,0.f,0.f,0.f};
    #pragma unroll
    for (int src = 0; src < 8; ++src) {
      floatx4 v = *reinterpret_cast<const floatx4*>(&red[((src*4 + jtR*2 + qR)*64 + lane)*4]);
      s[0]+=v[0]; s[1]+=v[1]; s[2]+=v[2]; s[3]+=v[3];
    }
    int jout = jh*64 + jtR*32 + col32;
    int Lb = 8*qR + 4*hi5;
    float* op = out + ((size_t)bi*Nc + jout)*Lc + Lb;
    #pragma unroll
    for (int c = 0; c < 4; ++c) op[c] = s[c] + b2v[Lb + c];
  }
}

extern "C" void kernel_launch(void* const* d_in, const int* in_sizes, int n_in,
                              void* d_out, int out_size, void* d_ws, size_t ws_size,
                              hipStream_t stream) {
  const float* AH = (const float*)d_in[0];
  const int*   ST = (const int*)d_in[1];
  const float* W1 = (const float*)d_in[2];
  const float* b1 = (const float*)d_in[3];
  const float* W2 = (const float*)d_in[4];
  const float* b2 = (const float*)d_in[5];
  float* out = (float*)d_out;

  char* ws = (char*)d_ws;
  unsigned short* con  = (unsigned short*)ws;                //   786,432 B
  unsigned short* w1mF = (unsigned short*)(ws +   786432);   // 1,572,864 B
  unsigned short* wPQF = (unsigned short*)(ws +  2359296);   // 3,145,728 B
  float* Pb = (float*)(ws + 5505024);                        // 2,097,152 B
  float* Q  = (float*)(ws + 7602176);                        // 2,097,152 B
  unsigned short* w2F2 = (unsigned short*)(ws + 9699328);    //    65,536 B

  k_prep<<<1680, 256, 0, stream>>>(AH, ST, W1, W2, con, w1mF, w2F2, wPQF);
  k_pq<<<256, 256, 0, stream>>>(con, wPQF, b1, Pb, Q);
  k_main<<<1024, 512, 0, stream>>>(con, w1mF, w2F2, Pb, Q, b2, out);
}